// Round 6
// baseline (175.150 us; speedup 1.0000x reference)
//
#include <hip/hip_runtime.h>
#include <hip/hip_bf16.h>

// EfficientSelfAttention (PVT-style), B=8, N=16384 (128x128), C=64, 1 head, SR=8.
// Round 6: fuse conv+LN+KV into one kernel (no atomics, no conv_out buffer,
// one fewer launch). attn kernel identical to round 5 (isolates the change).
//
// ws layout (bytes):
//   wbp   512KB @0        conv weights bf16 permuted
//   kbuf  256KB @524288   K bf16 [b][256][64]
//   vp    256KB @786432   V bf16 permuted [b][ks][g][ch][i]
//   qwb     8KB @1048576  q_w * scale, bf16
//   pwp     8KB @1056768  proj_w bf16, permuted
//   qb_s   256B @1064960  q_b * scale, f32

typedef __attribute__((ext_vector_type(8))) short bf16x8;
typedef __attribute__((ext_vector_type(4))) float f32x4;

__device__ __forceinline__ unsigned short f2bf(float f) {
    union { __hip_bfloat16 h; unsigned short u; } cv;
    cv.h = __hip_bfloat16(f);
    return cv.u;
}
union U8 { uint4 u; bf16x8 v; };
__device__ __forceinline__ bf16x8 pack8(float e0,float e1,float e2,float e3,
                                        float e4,float e5,float e6,float e7){
    U8 r;
    r.u.x = (unsigned)f2bf(e0) | ((unsigned)f2bf(e1)<<16);
    r.u.y = (unsigned)f2bf(e2) | ((unsigned)f2bf(e3)<<16);
    r.u.z = (unsigned)f2bf(e4) | ((unsigned)f2bf(e5)<<16);
    r.u.w = (unsigned)f2bf(e6) | ((unsigned)f2bf(e7)<<16);
    return r.v;
}
__device__ __forceinline__ bf16x8 ldg8(const unsigned short* p){
    U8 r; r.u = *(const uint4*)p; return r.v;
}

// ---------------- kernel 0: weight permutes ----------------------------------
__global__ __launch_bounds__(256) void prep_kernel(
    const float* __restrict__ sr_w,
    const float* __restrict__ q_w, const float* __restrict__ q_b,
    const float* __restrict__ proj_w,
    unsigned short* __restrict__ wbp,
    unsigned short* __restrict__ qwb, unsigned short* __restrict__ pwp,
    float* __restrict__ qb_s)
{
    int tid = blockIdx.x * 256 + threadIdx.x;   // 0..262143
    {   // wbp[((((w*4+kc)*32+ks)*4+g)*16+n)*8+i] = bf16(W[16w+n][kc*1024+ks*32+8g+i])
        int i = tid & 7, n = (tid>>3)&15, g = (tid>>7)&3, ks = (tid>>9)&31,
            kc = (tid>>14)&3, w = tid>>16;
        int co = 16*w + n;
        int k  = kc*1024 + ks*32 + 8*g + i;
        int kh = k >> 9, kw = (k>>6)&7, cin = k & 63;
        wbp[tid] = f2bf(sr_w[co*4096 + cin*64 + kh*8 + kw]);
    }
    if (tid < 4096)   qwb[tid] = f2bf(q_w[tid] * 0.125f);
    if (tid < 4096) { // pwp[((co*2+s3)*4+g)*8+i] = pw[co][16*(2s3+(i>>2))+4g+(i&3)]
        int i = tid & 7, g = (tid>>3)&3, s3 = (tid>>5)&1, co = tid>>6;
        int ch = 32*s3 + 16*(i>>2) + 4*g + (i&3);
        pwp[tid] = f2bf(proj_w[co*64 + ch]);
    }
    if (tid < 64) qb_s[tid] = q_b[tid] * 0.125f;
}

// ---------------- kernel 1: fused conv(8x8/8) + LayerNorm + KV proj ----------
// grid: b(8) x oh(16) = 128 blocks, 512 threads (8 waves).
// Wave w owns k-slice {kh = 4p + (w>>1), kw-half = w&1} per phase p; 64 MFMA/wave.
// Cross-wave f32 reduction in LDS, then per-wave LN (pos = w, w+8) + kv proj.
__global__ __launch_bounds__(512) void convln_kernel(
    const float* __restrict__ x, const unsigned short* __restrict__ wbp,
    const float* __restrict__ sr_b,
    const float* __restrict__ ln_g, const float* __restrict__ ln_b,
    const float* __restrict__ kv_w, const float* __restrict__ kv_b,
    unsigned short* __restrict__ kbuf, unsigned short* __restrict__ vp)
{
    __shared__ uint4 xsm4[4096];          // 64KB: stage 4 rows x 128 wi x 64 cin bf16 (swz);
    char* xsm = (char*)xsm4;              //        reused as red[8][16][64] f32 (swz) + ys
    float* red = (float*)xsm;             // 32KB
    float* ysp = (float*)(xsm + 49152);   // 16 x 64 f32 = 4KB (disjoint from red)

    int bid = blockIdx.x;
    int b = bid >> 4, oh = bid & 15;
    int t = threadIdx.x;
    int w = t >> 6, lane = t & 63, g = lane >> 4, n = lane & 15;

    f32x4 acc[4] = {{0,0,0,0},{0,0,0,0},{0,0,0,0},{0,0,0,0}};
    int khl = w >> 1;                     // row within phase (0..3)
    int kwh = w & 1;

    #pragma unroll
    for (int p = 0; p < 2; ++p) {
        // stage rows oh*8+4p .. +3 as bf16, XOR-swizzled by pos(=wi>>3)
        const float* slab = x + (size_t)(b*128 + oh*8 + 4*p) * 128 * 64;
        #pragma unroll
        for (int c2 = 0; c2 < 8; ++c2) {
            int eo = (c2*512 + t) * 8;
            float4 v0 = *(const float4*)(slab + eo);
            float4 v1 = *(const float4*)(slab + eo + 4);
            int byte = eo * 2;
            int dst = byte ^ (((byte >> 10) & 7) << 4);
            U8 tmp; tmp.v = pack8(v0.x,v0.y,v0.z,v0.w,v1.x,v1.y,v1.z,v1.w);
            *(uint4*)(xsm + dst) = tmp.u;
        }
        __syncthreads();

        int khp = 4*p + khl;              // global kh (0..7)
        int kc  = khp >> 1;
        int swz = (n & 7) << 4;
        #pragma unroll
        for (int j = 0; j < 8; ++j) {
            int ks  = (khp & 1)*16 + kwh*8 + j;
            int kw  = kwh*4 + (j >> 1);
            int cb  = ((j & 1) << 5) + 8*g;      // cin base
            int byte = khl*16384 + (n*8 + kw)*128 + cb*2;
            U8 Bx; Bx.u = *(const uint4*)(xsm + (byte ^ swz));
            #pragma unroll
            for (int tc = 0; tc < 4; ++tc) {
                bf16x8 A = ldg8(wbp + ((((tc*4 + kc)*32 + ks)*4 + g)*16 + n)*8);
                acc[tc] = __builtin_amdgcn_mfma_f32_16x16x32_bf16(A, Bx.v, acc[tc], 0, 0, 0);
            }
        }
        __syncthreads();
    }

    // dump partials: red[w][pos=n][co=16tc+4g..+3], XOR-swizzled by pos
    #pragma unroll
    for (int tc = 0; tc < 4; ++tc) {
        int byte = w*4096 + n*256 + (16*tc + 4*g)*4;
        *(f32x4*)(xsm + (byte ^ ((n & 7) << 4))) = acc[tc];
    }
    __syncthreads();

    // reduce over 8 waves + bias + LN + kv proj; wave w handles pos w and w+8
    int c = lane;
    #pragma unroll
    for (int pp = 0; pp < 2; ++pp) {
        int pos = w + 8*pp;
        int swzp = (pos & 7) << 4;
        float val = sr_b[c];
        #pragma unroll
        for (int w8 = 0; w8 < 8; ++w8)
            val += *(const float*)(xsm + ((w8*4096 + pos*256 + 4*c) ^ swzp));
        float s = val, s2 = val*val;
        #pragma unroll
        for (int o = 32; o >= 1; o >>= 1) {
            s  += __shfl_xor(s,  o, 64);
            s2 += __shfl_xor(s2, o, 64);
        }
        float mean = s * (1.f/64.f);
        float var  = s2 * (1.f/64.f) - mean*mean;
        float y = (val - mean) * rsqrtf(var + 1e-5f) * ln_g[c] + ln_b[c];
        ysp[pos*64 + c] = y;              // wave-local broadcast
        int m = oh*16 + pos;
        #pragma unroll
        for (int h = 0; h < 2; ++h) {
            int oc = c + h*64;
            float a2 = kv_b[oc];
            const float* wr = kv_w + oc*64;
            #pragma unroll
            for (int jj = 0; jj < 64; jj += 4) {
                float4 w4 = *(const float4*)(wr + jj);
                a2 += ysp[pos*64+jj]*w4.x + ysp[pos*64+jj+1]*w4.y
                    + ysp[pos*64+jj+2]*w4.z + ysp[pos*64+jj+3]*w4.w;
            }
            if (h == 0) {
                kbuf[(b*256 + m)*64 + c] = f2bf(a2);
            } else {    // vp[b][((ks*4+g)*64+ch)*8 + (m&3) + 4*hi]
                int ks2 = m >> 5, hi = (m >> 4) & 1, g2 = (m >> 2) & 3, r = m & 3;
                vp[(size_t)b*16384 + ((ks2*4 + g2)*64 + c)*8 + r + 4*hi] = f2bf(a2);
            }
        }
    }
}

// ---------------- kernel 2: fused q-proj/QK^T/softmax/PV/out-proj, all MFMA --
// (identical to round 5)
__global__ __launch_bounds__(512) void attn_kernel(
    const float* __restrict__ x,
    const unsigned short* __restrict__ qwb, const float* __restrict__ qb_s,
    const unsigned short* __restrict__ kbuf, const unsigned short* __restrict__ vp,
    const unsigned short* __restrict__ pwp, const float* __restrict__ proj_b,
    float* __restrict__ out)
{
    __shared__ char Ks[32768];   // K bf16 [256][64], XOR-swizzled rows
    int bid = blockIdx.x;
    int b = bid >> 7, rt = bid & 127;
    int t = threadIdx.x;
    {
        const char* kb = (const char*)(kbuf + (size_t)b*16384);
        #pragma unroll
        for (int c = 0; c < 4; ++c) {
            int off = (c*512 + t) * 16;
            int dst = off ^ (((off >> 7) & 7) << 4);
            *(uint4*)(Ks + dst) = *(const uint4*)(kb + off);
        }
    }
    __syncthreads();

    int w = t >> 6, lane = t & 63, g = lane >> 4, n = lane & 15;
    int qrow = rt*128 + w*16 + n;
    const float* xr = x + ((size_t)b*16384 + qrow) * 64;
    const char* vpb = (const char*)(vp + (size_t)b*16384);

    f32x4 qacc[4];
    #pragma unroll
    for (int tau = 0; tau < 4; ++tau)
        qacc[tau] = *(const f32x4*)(qb_s + 16*tau + 4*g);
    bf16x8 xq[2];
    #pragma unroll
    for (int s = 0; s < 2; ++s) {
        float4 v0 = *(const float4*)(xr + 32*s + 8*g);
        float4 v1 = *(const float4*)(xr + 32*s + 8*g + 4);
        xq[s] = pack8(v0.x,v0.y,v0.z,v0.w,v1.x,v1.y,v1.z,v1.w);
    }
    #pragma unroll
    for (int tau = 0; tau < 4; ++tau)
        #pragma unroll
        for (int s = 0; s < 2; ++s) {
            bf16x8 A = ldg8(qwb + (16*tau + n)*64 + 32*s + 8*g);
            qacc[tau] = __builtin_amdgcn_mfma_f32_16x16x32_bf16(A, xq[s], qacc[tau], 0,0,0);
        }
    bf16x8 qkB[2];
    #pragma unroll
    for (int s2 = 0; s2 < 2; ++s2)
        qkB[s2] = pack8(qacc[2*s2][0],  qacc[2*s2][1],  qacc[2*s2][2],  qacc[2*s2][3],
                        qacc[2*s2+1][0],qacc[2*s2+1][1],qacc[2*s2+1][2],qacc[2*s2+1][3]);

    float S[16][4];
    #pragma unroll
    for (int tt = 0; tt < 16; ++tt) {
        f32x4 sa = {0.f, 0.f, 0.f, 0.f};
        int m = 16*tt + n;
        int base = m * 128;
        int swz = (m & 7) << 4;
        #pragma unroll
        for (int s2 = 0; s2 < 2; ++s2) {
            int c1 = (32*s2 + 4*g) * 2;
            uint2 d0 = *(const uint2*)(Ks + ((base + c1)      ^ swz));
            uint2 d1 = *(const uint2*)(Ks + ((base + c1 + 32) ^ swz));
            U8 A; A.u = make_uint4(d0.x, d0.y, d1.x, d1.y);
            sa = __builtin_amdgcn_mfma_f32_16x16x32_bf16(A.v, qkB[s2], sa, 0,0,0);
        }
        S[tt][0]=sa[0]; S[tt][1]=sa[1]; S[tt][2]=sa[2]; S[tt][3]=sa[3];
    }

    float rm[16];
    #pragma unroll
    for (int tt = 0; tt < 16; ++tt)
        rm[tt] = fmaxf(fmaxf(S[tt][0],S[tt][1]), fmaxf(S[tt][2],S[tt][3]));
    float m8[8];
    #pragma unroll
    for (int j = 0; j < 8; ++j) m8[j] = fmaxf(rm[2*j], rm[2*j+1]);
    float mx = fmaxf(fmaxf(fmaxf(m8[0],m8[1]),fmaxf(m8[2],m8[3])),
                     fmaxf(fmaxf(m8[4],m8[5]),fmaxf(m8[6],m8[7])));
    mx = fmaxf(mx, __shfl_xor(mx, 16, 64));
    mx = fmaxf(mx, __shfl_xor(mx, 32, 64));
    #pragma unroll
    for (int tt = 0; tt < 16; ++tt)
        #pragma unroll
        for (int r = 0; r < 4; ++r)
            S[tt][r] = __expf(S[tt][r] - mx);
    float rs[16];
    #pragma unroll
    for (int tt = 0; tt < 16; ++tt) rs[tt] = (S[tt][0]+S[tt][1]) + (S[tt][2]+S[tt][3]);
    float s8[8];
    #pragma unroll
    for (int j = 0; j < 8; ++j) s8[j] = rs[2*j] + rs[2*j+1];
    float ssum = ((s8[0]+s8[1])+(s8[2]+s8[3])) + ((s8[4]+s8[5])+(s8[6]+s8[7]));
    ssum += __shfl_xor(ssum, 16, 64);
    ssum += __shfl_xor(ssum, 32, 64);
    float inv = 1.f / ssum;   // deferred: applied after PV

    f32x4 oacc[4] = {{0,0,0,0},{0,0,0,0},{0,0,0,0},{0,0,0,0}};
    #pragma unroll
    for (int ks = 0; ks < 8; ++ks) {
        bf16x8 Bp = pack8(S[2*ks][0],  S[2*ks][1],  S[2*ks][2],  S[2*ks][3],
                          S[2*ks+1][0],S[2*ks+1][1],S[2*ks+1][2],S[2*ks+1][3]);
        #pragma unroll
        for (int tc = 0; tc < 4; ++tc) {
            U8 A; A.u = *(const uint4*)(vpb + ((ks*4 + g)*64 + 16*tc + n) * 16);
            oacc[tc] = __builtin_amdgcn_mfma_f32_16x16x32_bf16(A.v, Bp, oacc[tc], 0,0,0);
        }
    }

    bf16x8 Bo[2];
    #pragma unroll
    for (int s3 = 0; s3 < 2; ++s3)
        Bo[s3] = pack8(oacc[2*s3][0]*inv,   oacc[2*s3][1]*inv,
                       oacc[2*s3][2]*inv,   oacc[2*s3][3]*inv,
                       oacc[2*s3+1][0]*inv, oacc[2*s3+1][1]*inv,
                       oacc[2*s3+1][2]*inv, oacc[2*s3+1][3]*inv);
    f32x4 pacc[4];
    #pragma unroll
    for (int tf = 0; tf < 4; ++tf)
        pacc[tf] = *(const f32x4*)(proj_b + 16*tf + 4*g);
    #pragma unroll
    for (int tf = 0; tf < 4; ++tf)
        #pragma unroll
        for (int s3 = 0; s3 < 2; ++s3) {
            bf16x8 Aw = ldg8(pwp + (((16*tf + n)*2 + s3)*4 + g)*8);
            pacc[tf] = __builtin_amdgcn_mfma_f32_16x16x32_bf16(Aw, Bo[s3], pacc[tf], 0,0,0);
        }
    float* orow = out + ((size_t)b*16384 + qrow) * 64;
    #pragma unroll
    for (int tf = 0; tf < 4; ++tf)
        *(float4*)(orow + 16*tf + 4*g) = *(float4*)&pacc[tf];
}

extern "C" void kernel_launch(void* const* d_in, const int* in_sizes, int n_in,
                              void* d_out, int out_size, void* d_ws, size_t ws_size,
                              hipStream_t stream)
{
    const float* x      = (const float*)d_in[0];
    const float* sr_w   = (const float*)d_in[1];
    const float* sr_b   = (const float*)d_in[2];
    const float* ln_g   = (const float*)d_in[3];
    const float* ln_b   = (const float*)d_in[4];
    const float* q_w    = (const float*)d_in[5];
    const float* q_b    = (const float*)d_in[6];
    const float* kv_w   = (const float*)d_in[7];
    const float* kv_b   = (const float*)d_in[8];
    const float* proj_w = (const float*)d_in[9];
    const float* proj_b = (const float*)d_in[10];
    float* out = (float*)d_out;

    char* wsb = (char*)d_ws;
    unsigned short* wbp  = (unsigned short*)(wsb);            // 512KB
    unsigned short* kbuf = (unsigned short*)(wsb + 524288);   // 256KB
    unsigned short* vp   = (unsigned short*)(wsb + 786432);   // 256KB
    unsigned short* qwb  = (unsigned short*)(wsb + 1048576);  // 8KB
    unsigned short* pwp  = (unsigned short*)(wsb + 1056768);  // 8KB
    float*          qb_s = (float*)(wsb + 1064960);           // 256B

    hipLaunchKernelGGL(prep_kernel, dim3(1024), dim3(256), 0, stream,
                       sr_w, q_w, q_b, proj_w, wbp, qwb, pwp, qb_s);
    hipLaunchKernelGGL(convln_kernel, dim3(128), dim3(512), 0, stream,
                       x, wbp, sr_b, ln_g, ln_b, kv_w, kv_b, kbuf, vp);
    hipLaunchKernelGGL(attn_kernel, dim3(1024), dim3(512), 0, stream,
                       x, qwb, qb_s, kbuf, vp, pwp, proj_b, out);
}

// Round 7
// 157.089 us; speedup vs baseline: 1.1150x; 1.1150x over previous
//
#include <hip/hip_runtime.h>
#include <hip/hip_bf16.h>

// EfficientSelfAttention (PVT-style), B=8, N=16384 (128x128), C=64, 1 head, SR=8.
// Round 7: fix prep (LDS-staged coalesced permute, was ~80us latency-bound at
// 256B-stride gather) and convln (512 blocks, 32KB LDS, single stage phase).
// attn kernel byte-identical to rounds 5/6.
//
// ws layout (bytes):
//   wbp   512KB @0        conv weights bf16 permuted [kh][j][tc][g][n][i]
//   kbuf  256KB @524288   K bf16 [b][256][64]
//   vp    256KB @786432   V bf16 permuted [b][ks][g][ch][i]
//   qwb     8KB @1048576  q_w * scale, bf16
//   pwp     8KB @1056768  proj_w bf16, permuted
//   qb_s   256B @1064960  q_b * scale, f32

typedef __attribute__((ext_vector_type(8))) short bf16x8;
typedef __attribute__((ext_vector_type(4))) float f32x4;

__device__ __forceinline__ unsigned short f2bf(float f) {
    union { __hip_bfloat16 h; unsigned short u; } cv;
    cv.h = __hip_bfloat16(f);
    return cv.u;
}
union U8 { uint4 u; bf16x8 v; };
__device__ __forceinline__ bf16x8 pack8(float e0,float e1,float e2,float e3,
                                        float e4,float e5,float e6,float e7){
    U8 r;
    r.u.x = (unsigned)f2bf(e0) | ((unsigned)f2bf(e1)<<16);
    r.u.y = (unsigned)f2bf(e2) | ((unsigned)f2bf(e3)<<16);
    r.u.z = (unsigned)f2bf(e4) | ((unsigned)f2bf(e5)<<16);
    r.u.w = (unsigned)f2bf(e6) | ((unsigned)f2bf(e7)<<16);
    return r.v;
}
__device__ __forceinline__ bf16x8 ldg8(const unsigned short* p){
    U8 r; r.u = *(const uint4*)p; return r.v;
}

// ---------------- kernel 0: weight permutes (LDS-staged, coalesced reads) ----
// grid 64 blocks (one per co), 256 threads.
// wbp[((((kh*16+j)*4+tc)*4+g)*16+n)*8+i] = bf16(sr_w[co][cin][kh][kw])
//   with co=16tc+n, kw=j>>1, cin=(j&1)*32+8g+i   (kappa = 8g+i per 32-chunk)
__global__ __launch_bounds__(256) void prep_kernel(
    const float* __restrict__ sr_w,
    const float* __restrict__ q_w, const float* __restrict__ q_b,
    const float* __restrict__ proj_w,
    unsigned short* __restrict__ wbp,
    unsigned short* __restrict__ qwb, unsigned short* __restrict__ pwp,
    float* __restrict__ qb_s)
{
    __shared__ float wsm[4096];          // one co-slice of sr_w, 16KB
    int co = blockIdx.x;
    int t  = threadIdx.x;
    #pragma unroll
    for (int u = 0; u < 4; ++u) {
        int e = (u*256 + t)*4;
        *(float4*)&wsm[e] = *(const float4*)(sr_w + (size_t)co*4096 + e);
    }
    __syncthreads();
    int tc = co >> 4, n = co & 15;
    #pragma unroll
    for (int u = 0; u < 2; ++u) {
        int gidx = t*2 + u;              // 0..511 = (kh, j, g)
        int g = gidx & 3, j = (gidx>>2) & 15, kh = gidx >> 6;
        int kw = j >> 1, cinb = (j&1)*32 + 8*g;
        float e[8];
        #pragma unroll
        for (int i = 0; i < 8; ++i)
            e[i] = wsm[(cinb + i)*64 + kh*8 + kw];
        U8 tmp; tmp.v = pack8(e[0],e[1],e[2],e[3],e[4],e[5],e[6],e[7]);
        *(uint4*)(wbp + (size_t)((((kh*16 + j)*4 + tc)*4 + g)*16 + n)*8) = tmp.u;
    }
    int tid = co*256 + t;                // 0..16383
    if (tid < 4096) qwb[tid] = f2bf(q_w[tid] * 0.125f);
    if (tid < 4096) { // pwp[((co2*2+s3)*4+g)*8+i] = pw[co2][16*(2s3+(i>>2))+4g+(i&3)]
        int i = tid & 7, g = (tid>>3)&3, s3 = (tid>>5)&1, co2 = tid>>6;
        int ch = 32*s3 + 16*(i>>2) + 4*g + (i&3);
        pwp[tid] = f2bf(proj_w[co2*64 + ch]);
    }
    if (tid < 64) qb_s[tid] = q_b[tid] * 0.125f;
}

// ---------------- kernel 1: fused conv(8x8/8) + LayerNorm + KV proj (v2) -----
// grid: b(8) x oh(16) x ow-quarter(4) = 512 blocks, 512 threads (8 waves).
// Patch [8 rows][32 wi][64 cin] bf16 = 32KB LDS. Wave w = kh; j(16) x tc(4)
// MFMA; output = 4 positions x 64 co; cross-wave f32 reduce in LDS; LN + KV
// on waves 0..3 (one position each).
__global__ __launch_bounds__(512) void convln_kernel(
    const float* __restrict__ x, const unsigned short* __restrict__ wbp,
    const float* __restrict__ sr_b,
    const float* __restrict__ ln_g, const float* __restrict__ ln_b,
    const float* __restrict__ kv_w, const float* __restrict__ kv_b,
    unsigned short* __restrict__ kbuf, unsigned short* __restrict__ vp)
{
    __shared__ char xsm[32768];          // patch; reused: red[8][4][64] f32 + ysp[4][64]
    int bid = blockIdx.x;
    int b = bid >> 6, oh = (bid >> 2) & 15, oq = bid & 3;
    int t = threadIdx.x;
    int w = t >> 6, lane = t & 63, g = lane >> 4, n = lane & 15;

    // stage: rows oh*8..+8, cols oq*32..+32, all cin (coalesced, 64KB f32 read)
    #pragma unroll
    for (int c2 = 0; c2 < 4; ++c2) {
        int eo = (c2*512 + t) * 8;       // 0..16383
        int r = eo >> 11, inrow = eo & 2047;
        const float* src = x + ((size_t)((b*128 + oh*8 + r)*128 + oq*32))*64 + inrow;
        float4 v0 = *(const float4*)(src);
        float4 v1 = *(const float4*)(src + 4);
        U8 tmp; tmp.v = pack8(v0.x,v0.y,v0.z,v0.w,v1.x,v1.y,v1.z,v1.w);
        *(uint4*)(xsm + eo*2) = tmp.u;
    }
    __syncthreads();

    int pos = n & 3;                     // lanes n>=4 compute duplicates (ignored)
    f32x4 acc[4] = {{0,0,0,0},{0,0,0,0},{0,0,0,0},{0,0,0,0}};
    #pragma unroll
    for (int j = 0; j < 16; ++j) {
        int byte = ((w*32 + pos*8 + (j>>1))*64 + (j&1)*32 + 8*g) * 2;
        U8 Bx; Bx.u = *(const uint4*)(xsm + byte);
        #pragma unroll
        for (int tc = 0; tc < 4; ++tc) {
            bf16x8 A = ldg8(wbp + (size_t)((((w*16 + j)*4 + tc)*4 + g)*16 + n)*8);
            acc[tc] = __builtin_amdgcn_mfma_f32_16x16x32_bf16(A, Bx.v, acc[tc], 0, 0, 0);
        }
    }
    __syncthreads();                     // patch now dead

    float* red = (float*)xsm;            // [w8(8)][pos(4)][co(64)] = 8KB
    float* ysp = (float*)(xsm + 8192);   // [pos(4)][64] = 1KB
    if (n < 4) {                         // D: row co=16tc+4g+r, col n=pos
        #pragma unroll
        for (int tc = 0; tc < 4; ++tc)
            *(f32x4*)(red + (w*4 + n)*64 + 16*tc + 4*g) = acc[tc];
    }
    __syncthreads();

    if (w < 4) {
        int p = w, c = lane;
        float val = sr_b[c];
        #pragma unroll
        for (int w8 = 0; w8 < 8; ++w8)
            val += red[(w8*4 + p)*64 + c];
        float s = val, s2 = val*val;
        #pragma unroll
        for (int o = 32; o >= 1; o >>= 1) {
            s  += __shfl_xor(s,  o, 64);
            s2 += __shfl_xor(s2, o, 64);
        }
        float mean = s * (1.f/64.f);
        float var  = s2 * (1.f/64.f) - mean*mean;
        float y = (val - mean) * rsqrtf(var + 1e-5f) * ln_g[c] + ln_b[c];
        ysp[p*64 + c] = y;
    }
    __syncthreads();
    if (w < 4) {
        int p = w, c = lane;
        int m = oh*16 + oq*4 + p;
        const float* yr = ysp + p*64;
        #pragma unroll
        for (int h = 0; h < 2; ++h) {
            int oc = c + h*64;
            float a2 = kv_b[oc];
            const float* wr = kv_w + oc*64;
            #pragma unroll
            for (int jj = 0; jj < 64; jj += 4) {
                float4 w4 = *(const float4*)(wr + jj);
                a2 += yr[jj]*w4.x + yr[jj+1]*w4.y + yr[jj+2]*w4.z + yr[jj+3]*w4.w;
            }
            if (h == 0) {
                kbuf[(b*256 + m)*64 + c] = f2bf(a2);
            } else {    // vp[b][((ks*4+g)*64+ch)*8 + (m&3) + 4*hi]
                int ks2 = m >> 5, hi = (m >> 4) & 1, g2 = (m >> 2) & 3, r = m & 3;
                vp[(size_t)b*16384 + ((ks2*4 + g2)*64 + c)*8 + r + 4*hi] = f2bf(a2);
            }
        }
    }
}

// ---------------- kernel 2: fused q-proj/QK^T/softmax/PV/out-proj, all MFMA --
// (identical to rounds 5/6)
__global__ __launch_bounds__(512) void attn_kernel(
    const float* __restrict__ x,
    const unsigned short* __restrict__ qwb, const float* __restrict__ qb_s,
    const unsigned short* __restrict__ kbuf, const unsigned short* __restrict__ vp,
    const unsigned short* __restrict__ pwp, const float* __restrict__ proj_b,
    float* __restrict__ out)
{
    __shared__ char Ks[32768];   // K bf16 [256][64], XOR-swizzled rows
    int bid = blockIdx.x;
    int b = bid >> 7, rt = bid & 127;
    int t = threadIdx.x;
    {
        const char* kb = (const char*)(kbuf + (size_t)b*16384);
        #pragma unroll
        for (int c = 0; c < 4; ++c) {
            int off = (c*512 + t) * 16;
            int dst = off ^ (((off >> 7) & 7) << 4);
            *(uint4*)(Ks + dst) = *(const uint4*)(kb + off);
        }
    }
    __syncthreads();

    int w = t >> 6, lane = t & 63, g = lane >> 4, n = lane & 15;
    int qrow = rt*128 + w*16 + n;
    const float* xr = x + ((size_t)b*16384 + qrow) * 64;
    const char* vpb = (const char*)(vp + (size_t)b*16384);

    f32x4 qacc[4];
    #pragma unroll
    for (int tau = 0; tau < 4; ++tau)
        qacc[tau] = *(const f32x4*)(qb_s + 16*tau + 4*g);
    bf16x8 xq[2];
    #pragma unroll
    for (int s = 0; s < 2; ++s) {
        float4 v0 = *(const float4*)(xr + 32*s + 8*g);
        float4 v1 = *(const float4*)(xr + 32*s + 8*g + 4);
        xq[s] = pack8(v0.x,v0.y,v0.z,v0.w,v1.x,v1.y,v1.z,v1.w);
    }
    #pragma unroll
    for (int tau = 0; tau < 4; ++tau)
        #pragma unroll
        for (int s = 0; s < 2; ++s) {
            bf16x8 A = ldg8(qwb + (16*tau + n)*64 + 32*s + 8*g);
            qacc[tau] = __builtin_amdgcn_mfma_f32_16x16x32_bf16(A, xq[s], qacc[tau], 0,0,0);
        }
    bf16x8 qkB[2];
    #pragma unroll
    for (int s2 = 0; s2 < 2; ++s2)
        qkB[s2] = pack8(qacc[2*s2][0],  qacc[2*s2][1],  qacc[2*s2][2],  qacc[2*s2][3],
                        qacc[2*s2+1][0],qacc[2*s2+1][1],qacc[2*s2+1][2],qacc[2*s2+1][3]);

    float S[16][4];
    #pragma unroll
    for (int tt = 0; tt < 16; ++tt) {
        f32x4 sa = {0.f, 0.f, 0.f, 0.f};
        int m = 16*tt + n;
        int base = m * 128;
        int swz = (m & 7) << 4;
        #pragma unroll
        for (int s2 = 0; s2 < 2; ++s2) {
            int c1 = (32*s2 + 4*g) * 2;
            uint2 d0 = *(const uint2*)(Ks + ((base + c1)      ^ swz));
            uint2 d1 = *(const uint2*)(Ks + ((base + c1 + 32) ^ swz));
            U8 A; A.u = make_uint4(d0.x, d0.y, d1.x, d1.y);
            sa = __builtin_amdgcn_mfma_f32_16x16x32_bf16(A.v, qkB[s2], sa, 0,0,0);
        }
        S[tt][0]=sa[0]; S[tt][1]=sa[1]; S[tt][2]=sa[2]; S[tt][3]=sa[3];
    }

    float rm[16];
    #pragma unroll
    for (int tt = 0; tt < 16; ++tt)
        rm[tt] = fmaxf(fmaxf(S[tt][0],S[tt][1]), fmaxf(S[tt][2],S[tt][3]));
    float m8[8];
    #pragma unroll
    for (int j = 0; j < 8; ++j) m8[j] = fmaxf(rm[2*j], rm[2*j+1]);
    float mx = fmaxf(fmaxf(fmaxf(m8[0],m8[1]),fmaxf(m8[2],m8[3])),
                     fmaxf(fmaxf(m8[4],m8[5]),fmaxf(m8[6],m8[7])));
    mx = fmaxf(mx, __shfl_xor(mx, 16, 64));
    mx = fmaxf(mx, __shfl_xor(mx, 32, 64));
    #pragma unroll
    for (int tt = 0; tt < 16; ++tt)
        #pragma unroll
        for (int r = 0; r < 4; ++r)
            S[tt][r] = __expf(S[tt][r] - mx);
    float rs[16];
    #pragma unroll
    for (int tt = 0; tt < 16; ++tt) rs[tt] = (S[tt][0]+S[tt][1]) + (S[tt][2]+S[tt][3]);
    float s8[8];
    #pragma unroll
    for (int j = 0; j < 8; ++j) s8[j] = rs[2*j] + rs[2*j+1];
    float ssum = ((s8[0]+s8[1])+(s8[2]+s8[3])) + ((s8[4]+s8[5])+(s8[6]+s8[7]));
    ssum += __shfl_xor(ssum, 16, 64);
    ssum += __shfl_xor(ssum, 32, 64);
    float inv = 1.f / ssum;   // deferred: applied after PV

    f32x4 oacc[4] = {{0,0,0,0},{0,0,0,0},{0,0,0,0},{0,0,0,0}};
    #pragma unroll
    for (int ks = 0; ks < 8; ++ks) {
        bf16x8 Bp = pack8(S[2*ks][0],  S[2*ks][1],  S[2*ks][2],  S[2*ks][3],
                          S[2*ks+1][0],S[2*ks+1][1],S[2*ks+1][2],S[2*ks+1][3]);
        #pragma unroll
        for (int tc = 0; tc < 4; ++tc) {
            U8 A; A.u = *(const uint4*)(vpb + ((ks*4 + g)*64 + 16*tc + n) * 16);
            oacc[tc] = __builtin_amdgcn_mfma_f32_16x16x32_bf16(A.v, Bp, oacc[tc], 0,0,0);
        }
    }

    bf16x8 Bo[2];
    #pragma unroll
    for (int s3 = 0; s3 < 2; ++s3)
        Bo[s3] = pack8(oacc[2*s3][0]*inv,   oacc[2*s3][1]*inv,
                       oacc[2*s3][2]*inv,   oacc[2*s3][3]*inv,
                       oacc[2*s3+1][0]*inv, oacc[2*s3+1][1]*inv,
                       oacc[2*s3+1][2]*inv, oacc[2*s3+1][3]*inv);
    f32x4 pacc[4];
    #pragma unroll
    for (int tf = 0; tf < 4; ++tf)
        pacc[tf] = *(const f32x4*)(proj_b + 16*tf + 4*g);
    #pragma unroll
    for (int tf = 0; tf < 4; ++tf)
        #pragma unroll
        for (int s3 = 0; s3 < 2; ++s3) {
            bf16x8 Aw = ldg8(pwp + (((16*tf + n)*2 + s3)*4 + g)*8);
            pacc[tf] = __builtin_amdgcn_mfma_f32_16x16x32_bf16(Aw, Bo[s3], pacc[tf], 0,0,0);
        }
    float* orow = out + ((size_t)b*16384 + qrow) * 64;
    #pragma unroll
    for (int tf = 0; tf < 4; ++tf)
        *(float4*)(orow + 16*tf + 4*g) = *(float4*)&pacc[tf];
}

extern "C" void kernel_launch(void* const* d_in, const int* in_sizes, int n_in,
                              void* d_out, int out_size, void* d_ws, size_t ws_size,
                              hipStream_t stream)
{
    const float* x      = (const float*)d_in[0];
    const float* sr_w   = (const float*)d_in[1];
    const float* sr_b   = (const float*)d_in[2];
    const float* ln_g   = (const float*)d_in[3];
    const float* ln_b   = (const float*)d_in[4];
    const float* q_w    = (const float*)d_in[5];
    const float* q_b    = (const float*)d_in[6];
    const float* kv_w   = (const float*)d_in[7];
    const float* kv_b   = (const float*)d_in[8];
    const float* proj_w = (const float*)d_in[9];
    const float* proj_b = (const float*)d_in[10];
    float* out = (float*)d_out;

    char* wsb = (char*)d_ws;
    unsigned short* wbp  = (unsigned short*)(wsb);            // 512KB
    unsigned short* kbuf = (unsigned short*)(wsb + 524288);   // 256KB
    unsigned short* vp   = (unsigned short*)(wsb + 786432);   // 256KB
    unsigned short* qwb  = (unsigned short*)(wsb + 1048576);  // 8KB
    unsigned short* pwp  = (unsigned short*)(wsb + 1056768);  // 8KB
    float*          qb_s = (float*)(wsb + 1064960);           // 256B

    hipLaunchKernelGGL(prep_kernel, dim3(64), dim3(256), 0, stream,
                       sr_w, q_w, q_b, proj_w, wbp, qwb, pwp, qb_s);
    hipLaunchKernelGGL(convln_kernel, dim3(512), dim3(512), 0, stream,
                       x, wbp, sr_b, ln_g, ln_b, kv_w, kv_b, kbuf, vp);
    hipLaunchKernelGGL(attn_kernel, dim3(1024), dim3(512), 0, stream,
                       x, qwb, qb_s, kbuf, vp, pwp, proj_b, out);
}